// Round 1
// baseline (106.272 us; speedup 1.0000x reference)
//
#include <hip/hip_runtime.h>
#include <math.h>

// Problem constants (match reference)
#define BB 4
#define SS 2048
#define EE 16
#define HH 4
#define DK 4
#define KS 4                  // key splits for parallelism
#define NQ (BB*HH*SS)         // 32768 total query rows
#define KLEN (SS/KS)          // 512 keys per split

// q stored pre-scaled by (1/sqrt(DK)) * log2(e) so the attn inner loop is
// pure exp2 domain with zero extra multiplies.
#define QSCALE 0.7213475204444817f   // 0.5 * log2(e)

// ---------------------------------------------------------------------------
// Kernel A: per-token projection. q = cos(x+theta)*QSCALE ; k = x@Wk^T ;
// v = x@Wv^T. Stored per-head-contiguous: qarr[(bh*S+s)*4], kv[(bh*S+s)*8]
// = {k0..k3, v0..v3} so the attention loop does one 32B uniform load per key.
// ---------------------------------------------------------------------------
__global__ __launch_bounds__(256) void proj_kernel(
    const float* __restrict__ x, const float* __restrict__ theta,
    const float* __restrict__ Wk, const float* __restrict__ Wv,
    float* __restrict__ qarr, float* __restrict__ kv)
{
    int t = blockIdx.x * 256 + threadIdx.x;   // token 0..8191
    int b = t >> 11;
    int s = t & (SS - 1);

    float xv[EE];
    const float4* xr = reinterpret_cast<const float4*>(x + t * EE);
    #pragma unroll
    for (int e4 = 0; e4 < 4; ++e4) {
        float4 v = xr[e4];
        xv[e4*4+0] = v.x; xv[e4*4+1] = v.y; xv[e4*4+2] = v.z; xv[e4*4+3] = v.w;
    }

    float qv[EE];
    #pragma unroll
    for (int e = 0; e < EE; ++e)
        qv[e] = __cosf(xv[e] + theta[e]) * QSCALE;   // theta[e]: uniform scalar load

    float kd[EE], vd[EE];
    #pragma unroll
    for (int d = 0; d < EE; ++d) {
        float ak = 0.f, av = 0.f;
        #pragma unroll
        for (int e = 0; e < EE; ++e) {
            ak = fmaf(xv[e], Wk[d*EE + e], ak);      // nn.Linear: x @ W^T
            av = fmaf(xv[e], Wv[d*EE + e], av);
        }
        kd[d] = ak; vd[d] = av;
    }

    #pragma unroll
    for (int h = 0; h < HH; ++h) {
        int gq = (b*HH + h)*SS + s;
        *reinterpret_cast<float4*>(qarr + (size_t)gq*4) =
            make_float4(qv[h*4+0], qv[h*4+1], qv[h*4+2], qv[h*4+3]);
        float4* kvp = reinterpret_cast<float4*>(kv + (size_t)gq*8);
        kvp[0] = make_float4(kd[h*4+0], kd[h*4+1], kd[h*4+2], kd[h*4+3]);
        kvp[1] = make_float4(vd[h*4+0], vd[h*4+1], vd[h*4+2], vd[h*4+3]);
    }
}

// ---------------------------------------------------------------------------
// Kernel B: flash attention without running max (scores bounded ~|10| -> safe
// in fp32). One thread per query row; loop over this block's key split.
// K/V address is wave-uniform -> scalar/broadcast loads.
// Writes partial acc[4] + l per (key-split, query).
// ---------------------------------------------------------------------------
__global__ __launch_bounds__(256) void attn_kernel(
    const float* __restrict__ qarr, const float* __restrict__ kv,
    float* __restrict__ accp, float* __restrict__ lp)
{
    int bh = blockIdx.z;                       // 0..15
    int ks = blockIdx.y;                       // 0..KS-1
    int qi = blockIdx.x * 256 + threadIdx.x;   // 0..S-1
    int gq = bh * SS + qi;

    float4 q = *reinterpret_cast<const float4*>(qarr + (size_t)gq*4);
    const float4* kvp =
        reinterpret_cast<const float4*>(kv + ((size_t)bh*SS + (size_t)ks*KLEN)*8);

    float l = 0.f;
    float ax = 0.f, ay = 0.f, az = 0.f, aw = 0.f;
    #pragma unroll 8
    for (int s = 0; s < KLEN; ++s) {
        float4 kk = kvp[2*s];
        float4 vv = kvp[2*s + 1];
        float sc = fmaf(q.x, kk.x, fmaf(q.y, kk.y, fmaf(q.z, kk.z, q.w*kk.w)));
        float p = exp2f(sc);                   // native v_exp_f32
        l += p;
        ax = fmaf(p, vv.x, ax);
        ay = fmaf(p, vv.y, ay);
        az = fmaf(p, vv.z, az);
        aw = fmaf(p, vv.w, aw);
    }

    *reinterpret_cast<float4*>(accp + ((size_t)ks*NQ + gq)*4) =
        make_float4(ax, ay, az, aw);
    lp[(size_t)ks*NQ + gq] = l;
}

// ---------------------------------------------------------------------------
// Kernel C: combine key-split partials, normalize, apply Wc. One thread per
// token (all H heads so the cross-head Wc mix is local).
// ---------------------------------------------------------------------------
__global__ __launch_bounds__(256) void out_kernel(
    const float* __restrict__ accp, const float* __restrict__ lp,
    const float* __restrict__ Wc, float* __restrict__ out)
{
    int t = blockIdx.x * 256 + threadIdx.x;   // token 0..8191
    int b = t >> 11;
    int s = t & (SS - 1);

    float attn[EE];
    #pragma unroll
    for (int h = 0; h < HH; ++h) {
        int gq = (b*HH + h)*SS + s;
        float ax = 0.f, ay = 0.f, az = 0.f, aw = 0.f, l = 0.f;
        #pragma unroll
        for (int ks = 0; ks < KS; ++ks) {
            float4 a = *reinterpret_cast<const float4*>(accp + ((size_t)ks*NQ + gq)*4);
            ax += a.x; ay += a.y; az += a.z; aw += a.w;
            l += lp[(size_t)ks*NQ + gq];
        }
        float inv = 1.0f / l;
        attn[h*4+0] = ax*inv; attn[h*4+1] = ay*inv;
        attn[h*4+2] = az*inv; attn[h*4+3] = aw*inv;
    }

    float4* orow = reinterpret_cast<float4*>(out + (size_t)t * EE);
    #pragma unroll
    for (int e4 = 0; e4 < 4; ++e4) {
        float o[4];
        #pragma unroll
        for (int i = 0; i < 4; ++i) {
            int e = e4*4 + i;
            float acc = 0.f;
            #pragma unroll
            for (int j = 0; j < EE; ++j)
                acc = fmaf(attn[j], Wc[e*EE + j], acc);   // out = attn @ Wc^T
            o[i] = acc;
        }
        orow[e4] = make_float4(o[0], o[1], o[2], o[3]);
    }
}

// ---------------------------------------------------------------------------
extern "C" void kernel_launch(void* const* d_in, const int* in_sizes, int n_in,
                              void* d_out, int out_size, void* d_ws, size_t ws_size,
                              hipStream_t stream)
{
    const float* x     = (const float*)d_in[0];
    const float* theta = (const float*)d_in[1];
    const float* Wk    = (const float*)d_in[2];
    const float* Wv    = (const float*)d_in[3];
    const float* Wc    = (const float*)d_in[4];
    float* out = (float*)d_out;

    // Workspace carve (floats): qarr 512KB | kv 1MB | accp 2MB | lp 512KB = 4MB
    float* ws   = (float*)d_ws;
    float* qarr = ws;                       // NQ*4
    float* kvb  = qarr + (size_t)NQ*4;      // NQ*8
    float* accp = kvb  + (size_t)NQ*8;      // KS*NQ*4
    float* lp   = accp + (size_t)KS*NQ*4;   // KS*NQ

    proj_kernel<<<dim3((BB*SS)/256), 256, 0, stream>>>(x, theta, Wk, Wv, qarr, kvb);
    attn_kernel<<<dim3(SS/256, KS, BB*HH), 256, 0, stream>>>(qarr, kvb, accp, lp);
    out_kernel<<<dim3((BB*SS)/256), 256, 0, stream>>>(accp, lp, Wc, out);
}

// Round 2
// 98.168 us; speedup vs baseline: 1.0825x; 1.0825x over previous
//
#include <hip/hip_runtime.h>
#include <math.h>

// Problem constants (match reference)
#define BB 4
#define SS 2048
#define EE 16
#define HH 4
#define DK 4
#define KS 8                  // key splits for parallelism
#define NQ (BB*HH*SS)         // 32768 total query rows
#define KLEN (SS/KS)          // 256 keys per split

// q stored pre-scaled by (1/sqrt(DK)) * log2(e) so the attn inner loop is
// pure exp2 domain with zero extra multiplies. No-running-max softmax is safe:
// |log2-score| <= ~16 worst-case -> exp2 sums stay far below fp32 overflow.
#define QSCALE 0.7213475204444817f   // 0.5 * log2(e)

// ---------------------------------------------------------------------------
// Kernel A: per-token projection. q = cos(x+theta)*QSCALE ; k = x@Wk^T ;
// v = x@Wv^T. Stored per-head-contiguous: qarr[(bh*S+s)*4], kv[(bh*S+s)*8]
// = {k0..k3, v0..v3} so the attention loop does one 32B uniform load per key.
// ---------------------------------------------------------------------------
__global__ __launch_bounds__(256) void proj_kernel(
    const float* __restrict__ x, const float* __restrict__ theta,
    const float* __restrict__ Wk, const float* __restrict__ Wv,
    float* __restrict__ qarr, float* __restrict__ kv)
{
    int t = blockIdx.x * 256 + threadIdx.x;   // token 0..8191
    int b = t >> 11;
    int s = t & (SS - 1);

    float xv[EE];
    const float4* xr = reinterpret_cast<const float4*>(x + t * EE);
    #pragma unroll
    for (int e4 = 0; e4 < 4; ++e4) {
        float4 v = xr[e4];
        xv[e4*4+0] = v.x; xv[e4*4+1] = v.y; xv[e4*4+2] = v.z; xv[e4*4+3] = v.w;
    }

    float qv[EE];
    #pragma unroll
    for (int e = 0; e < EE; ++e)
        qv[e] = __cosf(xv[e] + theta[e]) * QSCALE;   // theta[e]: uniform scalar load

    float kd[EE], vd[EE];
    #pragma unroll
    for (int d = 0; d < EE; ++d) {
        float ak = 0.f, av = 0.f;
        #pragma unroll
        for (int e = 0; e < EE; ++e) {
            ak = fmaf(xv[e], Wk[d*EE + e], ak);      // nn.Linear: x @ W^T
            av = fmaf(xv[e], Wv[d*EE + e], av);
        }
        kd[d] = ak; vd[d] = av;
    }

    #pragma unroll
    for (int h = 0; h < HH; ++h) {
        int gq = (b*HH + h)*SS + s;
        *reinterpret_cast<float4*>(qarr + (size_t)gq*4) =
            make_float4(qv[h*4+0], qv[h*4+1], qv[h*4+2], qv[h*4+3]);
        float4* kvp = reinterpret_cast<float4*>(kv + (size_t)gq*8);
        kvp[0] = make_float4(kd[h*4+0], kd[h*4+1], kd[h*4+2], kd[h*4+3]);
        kvp[1] = make_float4(vd[h*4+0], vd[h*4+1], vd[h*4+2], vd[h*4+3]);
    }
}

// ---------------------------------------------------------------------------
// Kernel B: flash attention without running max. Two queries per thread
// (amortizes the wave-uniform K/V load over 2 score rows). Native exp2.
// Writes partial acc[4] + l per (key-split, query).
// ---------------------------------------------------------------------------
__global__ __launch_bounds__(256) void attn_kernel(
    const float* __restrict__ qarr, const float* __restrict__ kv,
    float* __restrict__ accp, float* __restrict__ lp)
{
    int bh = blockIdx.z;                        // 0..15
    int ks = blockIdx.y;                        // 0..KS-1
    int qp = blockIdx.x * 256 + threadIdx.x;    // query-pair 0..S/2-1
    int gq0 = bh * SS + qp * 2;

    const float4* qp4 = reinterpret_cast<const float4*>(qarr + (size_t)gq0*4);
    float4 q0 = qp4[0];
    float4 q1 = qp4[1];
    const float4* kvp =
        reinterpret_cast<const float4*>(kv + ((size_t)bh*SS + (size_t)ks*KLEN)*8);

    float l0 = 0.f, l1 = 0.f;
    float a0x = 0.f, a0y = 0.f, a0z = 0.f, a0w = 0.f;
    float a1x = 0.f, a1y = 0.f, a1z = 0.f, a1w = 0.f;
    #pragma unroll 4
    for (int s = 0; s < KLEN; ++s) {
        float4 kk = kvp[2*s];
        float4 vv = kvp[2*s + 1];
        float sc0 = fmaf(q0.x, kk.x, fmaf(q0.y, kk.y, fmaf(q0.z, kk.z, q0.w*kk.w)));
        float sc1 = fmaf(q1.x, kk.x, fmaf(q1.y, kk.y, fmaf(q1.z, kk.z, q1.w*kk.w)));
        float p0 = __builtin_amdgcn_exp2f(sc0);   // native v_exp_f32
        float p1 = __builtin_amdgcn_exp2f(sc1);
        l0 += p0; l1 += p1;
        a0x = fmaf(p0, vv.x, a0x); a0y = fmaf(p0, vv.y, a0y);
        a0z = fmaf(p0, vv.z, a0z); a0w = fmaf(p0, vv.w, a0w);
        a1x = fmaf(p1, vv.x, a1x); a1y = fmaf(p1, vv.y, a1y);
        a1z = fmaf(p1, vv.z, a1z); a1w = fmaf(p1, vv.w, a1w);
    }

    float4* ap = reinterpret_cast<float4*>(accp + ((size_t)ks*NQ + gq0)*4);
    ap[0] = make_float4(a0x, a0y, a0z, a0w);
    ap[1] = make_float4(a1x, a1y, a1z, a1w);
    *reinterpret_cast<float2*>(lp + (size_t)ks*NQ + gq0) = make_float2(l0, l1);
}

// ---------------------------------------------------------------------------
// Kernel C: combine key-split partials, normalize, apply Wc. One thread per
// token (all H heads so the cross-head Wc mix is local).
// ---------------------------------------------------------------------------
__global__ __launch_bounds__(256) void out_kernel(
    const float* __restrict__ accp, const float* __restrict__ lp,
    const float* __restrict__ Wc, float* __restrict__ out)
{
    int t = blockIdx.x * 256 + threadIdx.x;   // token 0..8191
    int b = t >> 11;
    int s = t & (SS - 1);

    float attn[EE];
    #pragma unroll
    for (int h = 0; h < HH; ++h) {
        int gq = (b*HH + h)*SS + s;
        float ax = 0.f, ay = 0.f, az = 0.f, aw = 0.f, l = 0.f;
        #pragma unroll
        for (int ks = 0; ks < KS; ++ks) {
            float4 a = *reinterpret_cast<const float4*>(accp + ((size_t)ks*NQ + gq)*4);
            ax += a.x; ay += a.y; az += a.z; aw += a.w;
            l += lp[(size_t)ks*NQ + gq];
        }
        float inv = 1.0f / l;
        attn[h*4+0] = ax*inv; attn[h*4+1] = ay*inv;
        attn[h*4+2] = az*inv; attn[h*4+3] = aw*inv;
    }

    float4* orow = reinterpret_cast<float4*>(out + (size_t)t * EE);
    #pragma unroll
    for (int e4 = 0; e4 < 4; ++e4) {
        float o[4];
        #pragma unroll
        for (int i = 0; i < 4; ++i) {
            int e = e4*4 + i;
            float acc = 0.f;
            #pragma unroll
            for (int j = 0; j < EE; ++j)
                acc = fmaf(attn[j], Wc[e*EE + j], acc);   // out = attn @ Wc^T
            o[i] = acc;
        }
        orow[e4] = make_float4(o[0], o[1], o[2], o[3]);
    }
}

// ---------------------------------------------------------------------------
extern "C" void kernel_launch(void* const* d_in, const int* in_sizes, int n_in,
                              void* d_out, int out_size, void* d_ws, size_t ws_size,
                              hipStream_t stream)
{
    const float* x     = (const float*)d_in[0];
    const float* theta = (const float*)d_in[1];
    const float* Wk    = (const float*)d_in[2];
    const float* Wv    = (const float*)d_in[3];
    const float* Wc    = (const float*)d_in[4];
    float* out = (float*)d_out;

    // Workspace carve (floats): qarr 512KB | kv 1MB | accp 4MB | lp 1MB
    float* ws   = (float*)d_ws;
    float* qarr = ws;                       // NQ*4
    float* kvb  = qarr + (size_t)NQ*4;      // NQ*8
    float* accp = kvb  + (size_t)NQ*8;      // KS*NQ*4
    float* lp   = accp + (size_t)KS*NQ*4;   // KS*NQ

    proj_kernel<<<dim3((BB*SS)/256), 256, 0, stream>>>(x, theta, Wk, Wv, qarr, kvb);
    attn_kernel<<<dim3(SS/(2*256), KS, BB*HH), 256, 0, stream>>>(qarr, kvb, accp, lp);
    out_kernel<<<dim3((BB*SS)/256), 256, 0, stream>>>(accp, lp, Wc, out);
}